// Round 5
// baseline (105.436 us; speedup 1.0000x reference)
//
#include <hip/hip_runtime.h>

// Problem constants (match reference.py)
#define NCLASS 100
#define DDIM   512
#define NROWS  131072

#define CHUNK   1024                // rows per chunk
#define NCHUNK  (NROWS / CHUNK)     // 128
#define NSLICE  4                   // 128 cols per slice (64 lanes x float2)
#define THREADS 512                 // 8 waves
#define NWAVES  8

// Kernel 1: per-chunk counting sort by class; each wave owns a CONTIGUOUS
// class range so its rows are one contiguous segment of s_rows. Flat depth-4
// software-pipelined float2 stream with register accumulation; per-class
// flush = plain coalesced stores to per-chunk partial buffers. NO global
// atomics. Grid = 512 blocks = 2 blocks/CU so sorts/flushes of one block
// overlap the streaming of the other.
__global__ __launch_bounds__(THREADS, 4) void icv_accum_kernel(
    const float* __restrict__ feat,     // [NROWS][DDIM]
    const int*   __restrict__ labels,   // [NROWS]
    float*       __restrict__ sums_p,   // [NCHUNK][NCLASS][DDIM]
    float*       __restrict__ sq_p,     // [NCHUNK][NSLICE][NCLASS]
    int*         __restrict__ cnt_p)    // [NCHUNK][NCLASS]
{
    __shared__ int s_cnt[NCLASS];
    __shared__ int s_off[NCLASS + 1];
    __shared__ int s_pos[NCLASS];
    __shared__ int s_scan[128];
    __shared__ int s_rows[CHUNK];

    const int tid   = threadIdx.x;
    const int wave  = tid >> 6;
    const int lane  = tid & 63;
    const int slice = blockIdx.x & (NSLICE - 1);
    const int chunk = blockIdx.x >> 2;
    const int row0  = chunk * CHUNK;

    // ---- Phase A: counting sort of 1024 rows by class (2 rows/thread) ----
    if (tid < NCLASS) s_cnt[tid] = 0;
    __syncthreads();
    const int lab0 = labels[row0 + tid];              // coalesced
    const int lab1 = labels[row0 + THREADS + tid];
    atomicAdd(&s_cnt[lab0], 1);
    atomicAdd(&s_cnt[lab1], 1);
    __syncthreads();

    // exclusive prefix over 100 bins (128-wide Hillis-Steele)
    if (tid < 128) s_scan[tid] = (tid < NCLASS) ? s_cnt[tid] : 0;
    __syncthreads();
    #pragma unroll
    for (int d = 1; d < 128; d <<= 1) {
        int v = 0;
        if (tid < 128) { v = s_scan[tid]; if (tid >= d) v += s_scan[tid - d]; }
        __syncthreads();
        if (tid < 128) s_scan[tid] = v;
        __syncthreads();
    }
    if (tid < NCLASS) {
        const int e = s_scan[tid] - s_cnt[tid];
        s_off[tid] = e;
        s_pos[tid] = e;
    }
    if (tid == NCLASS) s_off[NCLASS] = CHUNK;
    __syncthreads();
    {
        const int p0 = atomicAdd(&s_pos[lab0], 1);
        s_rows[p0] = tid;
        const int p1 = atomicAdd(&s_pos[lab1], 1);
        s_rows[p1] = THREADS + tid;
    }
    if (slice == 0 && tid < NCLASS)
        cnt_p[chunk * NCLASS + tid] = s_cnt[tid];      // plain store
    __syncthreads();

    // ---- Phase B: flat stream over this wave's contiguous class range ----
    // wave w owns classes [lo, hi): 13 classes for w<4, else 12 (sums to 100)
    const int lo = wave * 12 + min(wave, 4);
    const int hi = lo + 12 + (wave < 4 ? 1 : 0);
    const int i0 = s_off[lo];
    const int i1 = s_off[hi];

    const float2* f2   = (const float2*)feat;          // row stride 256
    const size_t  base = (size_t)row0 * (DDIM / 2) + slice * 64 + lane;

    int    c    = lo;
    int    cend = s_off[c + 1];
    float2 acc  = make_float2(0.f, 0.f);
    float  sq   = 0.f;

#define LOADROW(idx) f2[base + (size_t)s_rows[(idx)] * (DDIM / 2)]

#define FLUSH() do {                                                          \
        float s_ = sq;                                                        \
        s_ += __shfl_xor(s_, 32, 64); s_ += __shfl_xor(s_, 16, 64);           \
        s_ += __shfl_xor(s_,  8, 64); s_ += __shfl_xor(s_,  4, 64);           \
        s_ += __shfl_xor(s_,  2, 64); s_ += __shfl_xor(s_,  1, 64);           \
        float2* dst_ = (float2*)(sums_p                                       \
            + ((size_t)(chunk * NCLASS + c) * DDIM) + slice * 128) + lane;    \
        *dst_ = acc;                                                          \
        if (lane == 0) sq_p[(chunk * NSLICE + slice) * NCLASS + c] = s_;      \
        acc = make_float2(0.f, 0.f); sq = 0.f;                                \
        ++c;                                                                  \
        cend = (c <= NCLASS - 1) ? s_off[c + 1] : (CHUNK + 1);                \
    } while (0)

#define STEP(K, RING) {                                                       \
        const int i_ = ib + (K);                                              \
        if (i_ < i1) {                                                        \
            while (i_ >= cend) FLUSH();                                       \
            const float2 x_ = RING;                                           \
            const int ip_ = i_ + 4;                                           \
            if (ip_ < i1) RING = LOADROW(ip_);                                \
            acc.x += x_.x; acc.y += x_.y;                                     \
            sq = fmaf(x_.x, x_.x, fmaf(x_.y, x_.y, sq));                      \
        }                                                                     \
    }

    float2 ring0 = make_float2(0.f, 0.f);
    float2 ring1 = ring0, ring2 = ring0, ring3 = ring0;
    if (i0 + 0 < i1) ring0 = LOADROW(i0 + 0);
    if (i0 + 1 < i1) ring1 = LOADROW(i0 + 1);
    if (i0 + 2 < i1) ring2 = LOADROW(i0 + 2);
    if (i0 + 3 < i1) ring3 = LOADROW(i0 + 3);

    for (int ib = i0; ib < i1; ib += 4) {
        STEP(0, ring0)
        STEP(1, ring1)
        STEP(2, ring2)
        STEP(3, ring3)
    }
    while (c < hi) FLUSH();                            // tail: remaining/empty classes
#undef STEP
#undef FLUSH
#undef LOADROW
}

// Kernel 2: per-class reduction of partials -> {trace_masked, valid}.
__global__ __launch_bounds__(512) void icv_reduce_kernel(
    const float* __restrict__ sums_p,   // [NCHUNK][NCLASS][DDIM]
    const float* __restrict__ sq_p,     // [NCHUNK][NSLICE][NCLASS]
    const int*   __restrict__ cnt_p,    // [NCHUNK][NCLASS]
    float*       __restrict__ cls_out)  // [NCLASS][2]
{
    __shared__ float sred[512];
    const int c = blockIdx.x;
    const int t = threadIdx.x;

    // column sum over chunks (thread t owns column t)
    float s = 0.f;
    const float* p = sums_p + (size_t)c * DDIM + t;
    #pragma unroll 8
    for (int ch = 0; ch < NCHUNK; ++ch)
        s += p[(size_t)ch * (NCLASS * DDIM)];
    sred[t] = s * s;
    __syncthreads();
    for (int d = 256; d > 0; d >>= 1) { if (t < d) sred[t] += sred[t + d]; __syncthreads(); }
    const float norm2 = sred[0];                       // ||sum_c||^2
    __syncthreads();

    sred[t] = sq_p[t * NCLASS + c];                    // NCHUNK*NSLICE == 512
    __syncthreads();
    for (int d = 256; d > 0; d >>= 1) { if (t < d) sred[t] += sred[t + d]; __syncthreads(); }
    const float sqtot = sred[0];
    __syncthreads();

    sred[t] = (t < NCHUNK) ? (float)cnt_p[t * NCLASS + c] : 0.f;
    __syncthreads();
    for (int d = 256; d > 0; d >>= 1) { if (t < d) sred[t] += sred[t + d]; __syncthreads(); }
    const float n = sred[0];

    if (t == 0) {
        const float safe  = fmaxf(n, 1.f);
        const float ssd   = sqtot - norm2 / safe;      // sq - n*||sums/n||^2
        const float trace = ssd / fmaxf(n - 1.f, 1.f);
        const bool  valid = (n >= 2.f);
        cls_out[c * 2 + 0] = valid ? trace : 0.f;
        cls_out[c * 2 + 1] = valid ? 1.f : 0.f;
    }
}

// Kernel 3: final valid-mean over 100 classes.
__global__ __launch_bounds__(128) void icv_final_kernel(
    const float* __restrict__ cls_out, float* __restrict__ out)
{
    __shared__ float st[128], sv[128];
    const int t = threadIdx.x;
    st[t] = (t < NCLASS) ? cls_out[t * 2 + 0] : 0.f;
    sv[t] = (t < NCLASS) ? cls_out[t * 2 + 1] : 0.f;
    __syncthreads();
    for (int d = 64; d > 0; d >>= 1) {
        if (t < d) { st[t] += st[t + d]; sv[t] += sv[t + d]; }
        __syncthreads();
    }
    if (t == 0) out[0] = (sv[0] > 0.f) ? (st[0] / fmaxf(sv[0], 1.f)) : 0.f;
}

extern "C" void kernel_launch(void* const* d_in, const int* in_sizes, int n_in,
                              void* d_out, int out_size, void* d_ws, size_t ws_size,
                              hipStream_t stream) {
    const float* feat   = (const float*)d_in[0];
    const int*   labels = (const int*)d_in[1];
    float* out = (float*)d_out;

    // Workspace layout (all written unconditionally -> no memset needed):
    // sums_p[NCHUNK][NCLASS][DDIM] f32   (26.2 MB)
    // sq_p  [NCHUNK][NSLICE][NCLASS] f32 (205 KB)
    // cnt_p [NCHUNK][NCLASS] i32         (51 KB)
    // cls_out[NCLASS][2] f32
    float* sums_p  = (float*)d_ws;
    float* sq_p    = sums_p + (size_t)NCHUNK * NCLASS * DDIM;
    int*   cnt_p   = (int*)(sq_p + NCHUNK * NSLICE * NCLASS);
    float* cls_out = (float*)(cnt_p + NCHUNK * NCLASS);

    icv_accum_kernel<<<dim3(NCHUNK * NSLICE), THREADS, 0, stream>>>(
        feat, labels, sums_p, sq_p, cnt_p);
    icv_reduce_kernel<<<dim3(NCLASS), 512, 0, stream>>>(
        sums_p, sq_p, cnt_p, cls_out);
    icv_final_kernel<<<dim3(1), 128, 0, stream>>>(cls_out, out);
}

// Round 6
// 84.774 us; speedup vs baseline: 1.2437x; 1.2437x over previous
//
#include <hip/hip_runtime.h>

// Problem constants (match reference.py)
#define NCLASS 100
#define DDIM   512
#define NROWS  131072

#define CHUNK    1024               // rows per chunk
#define NCHUNK   (NROWS / CHUNK)    // 128
#define NSLICE   2                  // 256 cols per slice (64 lanes x float4)
#define ATHREADS 1024               // accum threads (16 waves)
#define NWAVES   16
#define SPAN     (CHUNK / NWAVES)   // 64 rows per wave span (snap to class bounds)

// ---------------------------------------------------------------------------
// Kernel 0: per-chunk counting sort of labels (labels-only, tiny traffic).
// Emits: class-sorted global row ids, class offsets, counts, and per-wave
// class spans (wave w owns classes whose segment STARTS in [64w, 64w+64)).
// Also initializes the device sync counter used by the fused reduce/final.
// ---------------------------------------------------------------------------
__global__ __launch_bounds__(CHUNK) void icv_sort_kernel(
    const int* __restrict__ labels,
    int* __restrict__ rows_g,   // [NCHUNK][CHUNK]   global row ids, class-sorted
    int* __restrict__ off_g,    // [NCHUNK][NCLASS+1]
    int* __restrict__ cnt_p,    // [NCHUNK][NCLASS]
    int* __restrict__ span_g,   // [NCHUNK][NWAVES][2]
    int* __restrict__ sync_cnt)
{
    __shared__ int s_cnt[NCLASS];
    __shared__ int s_off[NCLASS + 1];
    __shared__ int s_pos[NCLASS];
    __shared__ int s_scan[128];
    __shared__ int s_rows[CHUNK];

    const int tid   = threadIdx.x;
    const int chunk = blockIdx.x;
    const int row0  = chunk * CHUNK;

    if (tid < NCLASS) s_cnt[tid] = 0;
    if (chunk == 0 && tid == 0) *sync_cnt = 0;     // re-init every call (poison-safe)
    __syncthreads();

    const int lab = labels[row0 + tid];            // coalesced, 1 row/thread
    atomicAdd(&s_cnt[lab], 1);
    __syncthreads();

    // exclusive prefix over 100 bins (128-wide Hillis-Steele)
    if (tid < 128) s_scan[tid] = (tid < NCLASS) ? s_cnt[tid] : 0;
    __syncthreads();
    #pragma unroll
    for (int d = 1; d < 128; d <<= 1) {
        int v = 0;
        if (tid < 128) { v = s_scan[tid]; if (tid >= d) v += s_scan[tid - d]; }
        __syncthreads();
        if (tid < 128) s_scan[tid] = v;
        __syncthreads();
    }
    if (tid < NCLASS) { const int e = s_scan[tid] - s_cnt[tid]; s_off[tid] = e; s_pos[tid] = e; }
    if (tid == NCLASS) s_off[NCLASS] = CHUNK;
    __syncthreads();

    { const int p = atomicAdd(&s_pos[lab], 1); s_rows[p] = row0 + tid; }

    // per-wave class spans: owner(c) = min(s_off[c]/SPAN, NWAVES-1); owner is
    // non-decreasing in c, so each wave owns a contiguous class range.
    if (tid < NWAVES) {
        int cf = NCLASS, ce = NCLASS;
        for (int c = 0; c < NCLASS; ++c) {
            int ow = s_off[c] / SPAN; if (ow > NWAVES - 1) ow = NWAVES - 1;
            if (ow == tid && cf == NCLASS) cf = c;
            if (ow > tid) { ce = c; break; }
        }
        if (cf > ce) cf = ce;                       // no class starts in this span
        span_g[(chunk * NWAVES + tid) * 2 + 0] = cf;
        span_g[(chunk * NWAVES + tid) * 2 + 1] = ce;
    }
    __syncthreads();

    rows_g[chunk * CHUNK + tid] = s_rows[tid];      // coalesced
    if (tid < NCLASS) {
        off_g[chunk * (NCLASS + 1) + tid] = s_off[tid];
        cnt_p[chunk * NCLASS + tid]       = s_cnt[tid];
    }
    if (tid == NCLASS) off_g[chunk * (NCLASS + 1) + NCLASS] = CHUNK;
}

// ---------------------------------------------------------------------------
// Kernel 1: pure streaming accumulation. Each wave streams its span's rows
// (float4/lane, depth-8 ring pipeline = 8 KB in flight per wave), register
// accumulation, per-class flush = plain coalesced stores. No sort, no
// atomics, no LDS RMW; s_rows reads are uniform broadcasts.
// ---------------------------------------------------------------------------
__global__ __launch_bounds__(ATHREADS) void icv_accum_kernel(
    const float* __restrict__ feat,     // [NROWS][DDIM]
    const int*   __restrict__ rows_g,
    const int*   __restrict__ off_g,
    const int*   __restrict__ span_g,
    float*       __restrict__ sums_p,   // [NCHUNK][NCLASS][DDIM]
    float*       __restrict__ sq_p)     // [NCHUNK][NSLICE][NCLASS]
{
    __shared__ int s_rows[CHUNK];
    __shared__ int s_off[NCLASS + 1];

    const int tid   = threadIdx.x;
    const int wave  = tid >> 6;
    const int lane  = tid & 63;
    const int slice = blockIdx.x & (NSLICE - 1);
    const int chunk = blockIdx.x >> 1;

    s_rows[tid] = rows_g[chunk * CHUNK + tid];
    if (tid < NCLASS + 1) s_off[tid] = off_g[chunk * (NCLASS + 1) + tid];
    __syncthreads();

    const int cf = span_g[(chunk * NWAVES + wave) * 2 + 0];
    const int ce = span_g[(chunk * NWAVES + wave) * 2 + 1];
    const int i0 = s_off[cf];
    const int i1 = s_off[ce];

    const float4* f4      = (const float4*)feat;       // row stride DDIM/4 = 128
    const int     colbase = slice * 64 + lane;

    int    c    = cf;
    int    cend = (c < ce) ? s_off[c + 1] : (CHUNK + 1);
    float4 acc  = make_float4(0.f, 0.f, 0.f, 0.f);
    float  sq   = 0.f;

#define LOADROW(idx) f4[(size_t)s_rows[(idx)] * (DDIM / 4) + colbase]

#define FLUSH() do {                                                          \
        float s_ = sq;                                                        \
        s_ += __shfl_xor(s_, 32, 64); s_ += __shfl_xor(s_, 16, 64);           \
        s_ += __shfl_xor(s_,  8, 64); s_ += __shfl_xor(s_,  4, 64);           \
        s_ += __shfl_xor(s_,  2, 64); s_ += __shfl_xor(s_,  1, 64);           \
        float4* dst_ = (float4*)(sums_p                                       \
            + ((size_t)(chunk * NCLASS + c) * DDIM) + slice * 256) + lane;    \
        *dst_ = acc;                                                          \
        if (lane == 0) sq_p[(chunk * NSLICE + slice) * NCLASS + c] = s_;      \
        acc = make_float4(0.f, 0.f, 0.f, 0.f); sq = 0.f;                      \
        ++c;                                                                  \
        cend = (c < ce) ? s_off[c + 1] : (CHUNK + 1);                         \
    } while (0)

#define STEP(K, RING) {                                                       \
        const int i_ = ib + (K);                                              \
        if (i_ < i1) {                                                        \
            while (i_ >= cend) FLUSH();                                       \
            const float4 x_ = RING;                                           \
            const int ip_ = i_ + 8;                                           \
            if (ip_ < i1) RING = LOADROW(ip_);                                \
            acc.x += x_.x; acc.y += x_.y; acc.z += x_.z; acc.w += x_.w;       \
            sq = fmaf(x_.x, x_.x, fmaf(x_.y, x_.y,                            \
                 fmaf(x_.z, x_.z, fmaf(x_.w, x_.w, sq))));                    \
        }                                                                     \
    }

    float4 r0 = make_float4(0.f, 0.f, 0.f, 0.f);
    float4 r1 = r0, r2 = r0, r3 = r0, r4 = r0, r5 = r0, r6 = r0, r7 = r0;
    if (i0 + 0 < i1) r0 = LOADROW(i0 + 0);
    if (i0 + 1 < i1) r1 = LOADROW(i0 + 1);
    if (i0 + 2 < i1) r2 = LOADROW(i0 + 2);
    if (i0 + 3 < i1) r3 = LOADROW(i0 + 3);
    if (i0 + 4 < i1) r4 = LOADROW(i0 + 4);
    if (i0 + 5 < i1) r5 = LOADROW(i0 + 5);
    if (i0 + 6 < i1) r6 = LOADROW(i0 + 6);
    if (i0 + 7 < i1) r7 = LOADROW(i0 + 7);

    for (int ib = i0; ib < i1; ib += 8) {
        STEP(0, r0) STEP(1, r1) STEP(2, r2) STEP(3, r3)
        STEP(4, r4) STEP(5, r5) STEP(6, r6) STEP(7, r7)
    }
    while (c < ce) FLUSH();                            // tail incl. empty classes
#undef STEP
#undef FLUSH
#undef LOADROW
}

// ---------------------------------------------------------------------------
// Kernel 2: per-class reduction of partials -> trace/valid, fused with the
// final valid-mean via last-block pattern (device-scope fence + atomic).
// ---------------------------------------------------------------------------
__global__ __launch_bounds__(512) void icv_reduce_kernel(
    const float* __restrict__ sums_p,   // [NCHUNK][NCLASS][DDIM]
    const float* __restrict__ sq_p,     // [NCHUNK][NSLICE][NCLASS]
    const int*   __restrict__ cnt_p,    // [NCHUNK][NCLASS]
    float*       __restrict__ cls_out,  // [NCLASS][2]
    int*         __restrict__ sync_cnt,
    float*       __restrict__ out)
{
    __shared__ float red[3][8];
    __shared__ float fin[2][8];
    __shared__ int   s_last;

    const int c    = blockIdx.x;
    const int t    = threadIdx.x;
    const int wave = t >> 6;
    const int lane = t & 63;

    // thread t owns column t of class c, summed over chunks
    float s = 0.f;
    const float* p = sums_p + (size_t)c * DDIM + t;
    #pragma unroll 8
    for (int ch = 0; ch < NCHUNK; ++ch)
        s += p[(size_t)ch * (NCLASS * DDIM)];

    float v1 = s * s;                                          // -> ||sum_c||^2
    float v2 = (t < NCHUNK * NSLICE) ? sq_p[t * NCLASS + c] : 0.f;
    float v3 = (t < NCHUNK) ? (float)cnt_p[t * NCLASS + c] : 0.f;
    #pragma unroll
    for (int off = 32; off > 0; off >>= 1) {
        v1 += __shfl_xor(v1, off, 64);
        v2 += __shfl_xor(v2, off, 64);
        v3 += __shfl_xor(v3, off, 64);
    }
    if (lane == 0) { red[0][wave] = v1; red[1][wave] = v2; red[2][wave] = v3; }
    __syncthreads();

    if (t == 0) {
        float n2 = 0.f, sq = 0.f, n = 0.f;
        #pragma unroll
        for (int w = 0; w < 8; ++w) { n2 += red[0][w]; sq += red[1][w]; n += red[2][w]; }
        const float safe  = fmaxf(n, 1.f);
        const float ssd   = sq - n2 / safe;        // sq - n*||sums/n||^2
        const float trace = ssd / fmaxf(n - 1.f, 1.f);
        const bool  valid = (n >= 2.f);
        cls_out[c * 2 + 0] = valid ? trace : 0.f;
        cls_out[c * 2 + 1] = valid ? 1.f : 0.f;
        __threadfence();                           // release class result
        const int done = atomicAdd(sync_cnt, 1);   // device-scope
        s_last = (done == NCLASS - 1) ? 1 : 0;
    }
    __syncthreads();

    if (s_last) {                                  // uniform across block
        __threadfence();                           // acquire others' results
        float tv = 0.f, vv = 0.f;
        if (t < NCLASS) {
            const volatile float* cv = (const volatile float*)cls_out;
            tv = cv[t * 2 + 0];
            vv = cv[t * 2 + 1];
        }
        #pragma unroll
        for (int off = 32; off > 0; off >>= 1) {
            tv += __shfl_xor(tv, off, 64);
            vv += __shfl_xor(vv, off, 64);
        }
        if (lane == 0) { fin[0][wave] = tv; fin[1][wave] = vv; }
        __syncthreads();
        if (t == 0) {
            float tot = 0.f, vc = 0.f;
            #pragma unroll
            for (int w = 0; w < 8; ++w) { tot += fin[0][w]; vc += fin[1][w]; }
            out[0] = (vc > 0.f) ? (tot / fmaxf(vc, 1.f)) : 0.f;
        }
    }
}

extern "C" void kernel_launch(void* const* d_in, const int* in_sizes, int n_in,
                              void* d_out, int out_size, void* d_ws, size_t ws_size,
                              hipStream_t stream) {
    const float* feat   = (const float*)d_in[0];
    const int*   labels = (const int*)d_in[1];
    float* out = (float*)d_out;

    // Workspace (all slots written unconditionally every call -> no memset):
    float* sums_p  = (float*)d_ws;                              // 26.2 MB
    float* sq_p    = sums_p + (size_t)NCHUNK * NCLASS * DDIM;   // 102 KB
    int*   cnt_p   = (int*)(sq_p + NCHUNK * NSLICE * NCLASS);   // 51 KB
    int*   rows_g  = cnt_p + NCHUNK * NCLASS;                   // 524 KB
    int*   off_g   = rows_g + NCHUNK * CHUNK;                   // 52 KB
    int*   span_g  = off_g + NCHUNK * (NCLASS + 1);             // 16 KB
    float* cls_out = (float*)(span_g + NCHUNK * NWAVES * 2);
    int*   sync_cnt= (int*)(cls_out + NCLASS * 2);

    icv_sort_kernel<<<dim3(NCHUNK), CHUNK, 0, stream>>>(
        labels, rows_g, off_g, cnt_p, span_g, sync_cnt);
    icv_accum_kernel<<<dim3(NCHUNK * NSLICE), ATHREADS, 0, stream>>>(
        feat, rows_g, off_g, span_g, sums_p, sq_p);
    icv_reduce_kernel<<<dim3(NCLASS), 512, 0, stream>>>(
        sums_p, sq_p, cnt_p, cls_out, sync_cnt, out);
}

// Round 7
// 82.179 us; speedup vs baseline: 1.2830x; 1.0316x over previous
//
#include <hip/hip_runtime.h>

// Problem constants (match reference.py)
#define NCLASS 100
#define DDIM   512
#define NROWS  131072

#define CHUNK    2048               // rows per chunk (partials scale ~1/CHUNK)
#define NCHUNK   (NROWS / CHUNK)    // 64
#define NSLICE   2                  // 256 cols per slice (64 lanes x float4)
#define NSPLIT   4                  // row-splits per (chunk, slice)
#define AWAVES   8                  // waves per accum block
#define WSLOTS   (NSPLIT * AWAVES)  // 32 wave-slots per chunk
#define SPAN     (CHUNK / WSLOTS)   // 64 rows nominal per wave-slot
#define ATHREADS 512
#define STHREADS 1024

// ---------------------------------------------------------------------------
// Kernel 0: per-chunk counting sort of labels (labels-only). Emits class-
// sorted global row ids, class offsets, counts, and 32 per-chunk wave-slot
// class spans (slot s owns classes whose segment STARTS in [64s, 64(s+1))).
// Each class belongs to exactly one slot -> every partial written once.
// ---------------------------------------------------------------------------
__global__ __launch_bounds__(STHREADS) void icv_sort_kernel(
    const int* __restrict__ labels,
    int* __restrict__ rows_g,   // [NCHUNK][CHUNK] global row ids, class-sorted
    int* __restrict__ off_g,    // [NCHUNK][NCLASS+1]
    int* __restrict__ cnt_p,    // [NCHUNK][NCLASS]
    int* __restrict__ span_g,   // [NCHUNK][WSLOTS][2]
    int* __restrict__ sync_cnt)
{
    __shared__ int s_cnt[NCLASS];
    __shared__ int s_off[NCLASS + 1];
    __shared__ int s_pos[NCLASS];
    __shared__ int s_scan[128];
    __shared__ int s_rows[CHUNK];

    const int tid   = threadIdx.x;
    const int chunk = blockIdx.x;
    const int row0  = chunk * CHUNK;

    if (tid < NCLASS) s_cnt[tid] = 0;
    if (chunk == 0 && tid == 0) *sync_cnt = 0;     // re-init every call
    __syncthreads();

    const int lab0 = labels[row0 + tid];           // coalesced, 2 rows/thread
    const int lab1 = labels[row0 + STHREADS + tid];
    atomicAdd(&s_cnt[lab0], 1);
    atomicAdd(&s_cnt[lab1], 1);
    __syncthreads();

    // exclusive prefix over 100 bins (128-wide Hillis-Steele)
    if (tid < 128) s_scan[tid] = (tid < NCLASS) ? s_cnt[tid] : 0;
    __syncthreads();
    #pragma unroll
    for (int d = 1; d < 128; d <<= 1) {
        int v = 0;
        if (tid < 128) { v = s_scan[tid]; if (tid >= d) v += s_scan[tid - d]; }
        __syncthreads();
        if (tid < 128) s_scan[tid] = v;
        __syncthreads();
    }
    if (tid < NCLASS) { const int e = s_scan[tid] - s_cnt[tid]; s_off[tid] = e; s_pos[tid] = e; }
    if (tid == NCLASS) s_off[NCLASS] = CHUNK;
    __syncthreads();

    { const int p0 = atomicAdd(&s_pos[lab0], 1); s_rows[p0] = row0 + tid; }
    { const int p1 = atomicAdd(&s_pos[lab1], 1); s_rows[p1] = row0 + STHREADS + tid; }

    // wave-slot class spans: owner(c) = min(s_off[c]/SPAN, WSLOTS-1);
    // owner is non-decreasing in c -> contiguous class ranges, full partition.
    if (tid < WSLOTS) {
        int cf = NCLASS, ce = NCLASS;
        for (int c = 0; c < NCLASS; ++c) {
            int ow = s_off[c] / SPAN; if (ow > WSLOTS - 1) ow = WSLOTS - 1;
            if (ow == tid && cf == NCLASS) cf = c;
            if (ow > tid) { ce = c; break; }
        }
        if (cf > ce) cf = ce;                      // empty slot
        span_g[(chunk * WSLOTS + tid) * 2 + 0] = cf;
        span_g[(chunk * WSLOTS + tid) * 2 + 1] = ce;
    }
    __syncthreads();

    rows_g[chunk * CHUNK + tid]            = s_rows[tid];
    rows_g[chunk * CHUNK + STHREADS + tid] = s_rows[STHREADS + tid];
    if (tid < NCLASS) {
        off_g[chunk * (NCLASS + 1) + tid] = s_off[tid];
        cnt_p[chunk * NCLASS + tid]       = s_cnt[tid];
    }
    if (tid == NCLASS) off_g[chunk * (NCLASS + 1) + NCLASS] = CHUNK;
}

// ---------------------------------------------------------------------------
// Kernel 1: pure streaming accumulation. Grid = 64 chunks x 2 slices x 4
// row-splits = 512 blocks of 512 threads (2 blocks/CU). Wave-slot ws =
// split*8 + wave streams its snapped class span: float4/lane, depth-8 ring,
// register accumulation, per-class flush = plain coalesced stores.
// ---------------------------------------------------------------------------
__global__ __launch_bounds__(ATHREADS, 4) void icv_accum_kernel(
    const float* __restrict__ feat,     // [NROWS][DDIM]
    const int*   __restrict__ rows_g,
    const int*   __restrict__ off_g,
    const int*   __restrict__ span_g,
    float*       __restrict__ sums_p,   // [NCHUNK][NCLASS][DDIM]
    float*       __restrict__ sq_p)     // [NCHUNK][NSLICE][NCLASS]
{
    __shared__ int s_rows[CHUNK];       // 8 KB
    __shared__ int s_off[NCLASS + 1];

    const int tid   = threadIdx.x;
    const int wave  = tid >> 6;
    const int lane  = tid & 63;
    const int b     = blockIdx.x;
    const int chunk = b >> 3;
    const int slice = b & 1;
    const int split = (b >> 1) & 3;

    #pragma unroll
    for (int k = 0; k < CHUNK / ATHREADS; ++k)
        s_rows[k * ATHREADS + tid] = rows_g[chunk * CHUNK + k * ATHREADS + tid];
    if (tid < NCLASS + 1) s_off[tid] = off_g[chunk * (NCLASS + 1) + tid];
    __syncthreads();

    const int ws = split * AWAVES + wave;
    const int cf = span_g[(chunk * WSLOTS + ws) * 2 + 0];
    const int ce = span_g[(chunk * WSLOTS + ws) * 2 + 1];
    const int i0 = s_off[cf];
    const int i1 = s_off[ce];

    const float4* f4      = (const float4*)feat;   // row stride DDIM/4 = 128
    const int     colbase = slice * 64 + lane;

    int    c    = cf;
    int    cend = (c < ce) ? s_off[c + 1] : (CHUNK + 1);
    float4 acc  = make_float4(0.f, 0.f, 0.f, 0.f);
    float  sq   = 0.f;

#define LOADROW(idx) f4[(size_t)s_rows[(idx)] * (DDIM / 4) + colbase]

#define FLUSH() do {                                                          \
        float s_ = sq;                                                        \
        s_ += __shfl_xor(s_, 32, 64); s_ += __shfl_xor(s_, 16, 64);           \
        s_ += __shfl_xor(s_,  8, 64); s_ += __shfl_xor(s_,  4, 64);           \
        s_ += __shfl_xor(s_,  2, 64); s_ += __shfl_xor(s_,  1, 64);           \
        float4* dst_ = (float4*)(sums_p                                       \
            + ((size_t)(chunk * NCLASS + c) * DDIM) + slice * 256) + lane;    \
        *dst_ = acc;                                                          \
        if (lane == 0) sq_p[(chunk * NSLICE + slice) * NCLASS + c] = s_;      \
        acc = make_float4(0.f, 0.f, 0.f, 0.f); sq = 0.f;                      \
        ++c;                                                                  \
        cend = (c < ce) ? s_off[c + 1] : (CHUNK + 1);                         \
    } while (0)

#define STEP(K, RING) {                                                       \
        const int i_ = ib + (K);                                              \
        if (i_ < i1) {                                                        \
            while (i_ >= cend) FLUSH();                                       \
            const float4 x_ = RING;                                           \
            const int ip_ = i_ + 8;                                           \
            if (ip_ < i1) RING = LOADROW(ip_);                                \
            acc.x += x_.x; acc.y += x_.y; acc.z += x_.z; acc.w += x_.w;       \
            sq = fmaf(x_.x, x_.x, fmaf(x_.y, x_.y,                            \
                 fmaf(x_.z, x_.z, fmaf(x_.w, x_.w, sq))));                    \
        }                                                                     \
    }

    float4 r0 = make_float4(0.f, 0.f, 0.f, 0.f);
    float4 r1 = r0, r2 = r0, r3 = r0, r4 = r0, r5 = r0, r6 = r0, r7 = r0;
    if (i0 + 0 < i1) r0 = LOADROW(i0 + 0);
    if (i0 + 1 < i1) r1 = LOADROW(i0 + 1);
    if (i0 + 2 < i1) r2 = LOADROW(i0 + 2);
    if (i0 + 3 < i1) r3 = LOADROW(i0 + 3);
    if (i0 + 4 < i1) r4 = LOADROW(i0 + 4);
    if (i0 + 5 < i1) r5 = LOADROW(i0 + 5);
    if (i0 + 6 < i1) r6 = LOADROW(i0 + 6);
    if (i0 + 7 < i1) r7 = LOADROW(i0 + 7);

    for (int ib = i0; ib < i1; ib += 8) {
        STEP(0, r0) STEP(1, r1) STEP(2, r2) STEP(3, r3)
        STEP(4, r4) STEP(5, r5) STEP(6, r6) STEP(7, r7)
    }
    while (c < ce) FLUSH();                        // tail incl. empty classes
#undef STEP
#undef FLUSH
#undef LOADROW
}

// ---------------------------------------------------------------------------
// Kernel 2: per-class reduction of partials -> trace/valid, fused with the
// final valid-mean via last-block pattern (device-scope fence + atomic).
// ---------------------------------------------------------------------------
__global__ __launch_bounds__(512) void icv_reduce_kernel(
    const float* __restrict__ sums_p,   // [NCHUNK][NCLASS][DDIM]
    const float* __restrict__ sq_p,     // [NCHUNK][NSLICE][NCLASS]
    const int*   __restrict__ cnt_p,    // [NCHUNK][NCLASS]
    float*       __restrict__ cls_out,  // [NCLASS][2]
    int*         __restrict__ sync_cnt,
    float*       __restrict__ out)
{
    __shared__ float red[3][8];
    __shared__ float fin[2][8];
    __shared__ int   s_last;

    const int c    = blockIdx.x;
    const int t    = threadIdx.x;
    const int wave = t >> 6;
    const int lane = t & 63;

    // thread t owns column t of class c, summed over chunks
    float s = 0.f;
    const float* p = sums_p + (size_t)c * DDIM + t;
    #pragma unroll 8
    for (int ch = 0; ch < NCHUNK; ++ch)
        s += p[(size_t)ch * (NCLASS * DDIM)];

    float v1 = s * s;                                          // -> ||sum_c||^2
    float v2 = (t < NCHUNK * NSLICE) ? sq_p[t * NCLASS + c] : 0.f;
    float v3 = (t < NCHUNK) ? (float)cnt_p[t * NCLASS + c] : 0.f;
    #pragma unroll
    for (int off = 32; off > 0; off >>= 1) {
        v1 += __shfl_xor(v1, off, 64);
        v2 += __shfl_xor(v2, off, 64);
        v3 += __shfl_xor(v3, off, 64);
    }
    if (lane == 0) { red[0][wave] = v1; red[1][wave] = v2; red[2][wave] = v3; }
    __syncthreads();

    if (t == 0) {
        float n2 = 0.f, sq = 0.f, n = 0.f;
        #pragma unroll
        for (int w = 0; w < 8; ++w) { n2 += red[0][w]; sq += red[1][w]; n += red[2][w]; }
        const float safe  = fmaxf(n, 1.f);
        const float ssd   = sq - n2 / safe;        // sq - n*||sums/n||^2
        const float trace = ssd / fmaxf(n - 1.f, 1.f);
        const bool  valid = (n >= 2.f);
        cls_out[c * 2 + 0] = valid ? trace : 0.f;
        cls_out[c * 2 + 1] = valid ? 1.f : 0.f;
        __threadfence();                           // release class result
        const int done = atomicAdd(sync_cnt, 1);   // device-scope
        s_last = (done == NCLASS - 1) ? 1 : 0;
    }
    __syncthreads();

    if (s_last) {                                  // uniform across block
        __threadfence();                           // acquire others' results
        float tv = 0.f, vv = 0.f;
        if (t < NCLASS) {
            const volatile float* cv = (const volatile float*)cls_out;
            tv = cv[t * 2 + 0];
            vv = cv[t * 2 + 1];
        }
        #pragma unroll
        for (int off = 32; off > 0; off >>= 1) {
            tv += __shfl_xor(tv, off, 64);
            vv += __shfl_xor(vv, off, 64);
        }
        if (lane == 0) { fin[0][wave] = tv; fin[1][wave] = vv; }
        __syncthreads();
        if (t == 0) {
            float tot = 0.f, vc = 0.f;
            #pragma unroll
            for (int w = 0; w < 8; ++w) { tot += fin[0][w]; vc += fin[1][w]; }
            out[0] = (vc > 0.f) ? (tot / fmaxf(vc, 1.f)) : 0.f;
        }
    }
}

extern "C" void kernel_launch(void* const* d_in, const int* in_sizes, int n_in,
                              void* d_out, int out_size, void* d_ws, size_t ws_size,
                              hipStream_t stream) {
    const float* feat   = (const float*)d_in[0];
    const int*   labels = (const int*)d_in[1];
    float* out = (float*)d_out;

    // Workspace (all slots written unconditionally every call -> no memset):
    float* sums_p  = (float*)d_ws;                              // 13.1 MB
    float* sq_p    = sums_p + (size_t)NCHUNK * NCLASS * DDIM;   // 51 KB
    int*   cnt_p   = (int*)(sq_p + NCHUNK * NSLICE * NCLASS);   // 26 KB
    int*   rows_g  = cnt_p + NCHUNK * NCLASS;                   // 524 KB
    int*   off_g   = rows_g + NCHUNK * CHUNK;                   // 26 KB
    int*   span_g  = off_g + NCHUNK * (NCLASS + 1);             // 16 KB
    float* cls_out = (float*)(span_g + NCHUNK * WSLOTS * 2);
    int*   sync_cnt= (int*)(cls_out + NCLASS * 2);

    icv_sort_kernel<<<dim3(NCHUNK), STHREADS, 0, stream>>>(
        labels, rows_g, off_g, cnt_p, span_g, sync_cnt);
    icv_accum_kernel<<<dim3(NCHUNK * NSLICE * NSPLIT), ATHREADS, 0, stream>>>(
        feat, rows_g, off_g, span_g, sums_p, sq_p);
    icv_reduce_kernel<<<dim3(NCLASS), 512, 0, stream>>>(
        sums_p, sq_p, cnt_p, cls_out, sync_cnt, out);
}

// Round 8
// 73.993 us; speedup vs baseline: 1.4249x; 1.1106x over previous
//
#include <hip/hip_runtime.h>

// Problem constants (match reference.py)
#define NCLASS 100
#define DDIM   512
#define NROWS  131072

#define CHUNK    2048               // rows per chunk
#define NCHUNK   (NROWS / CHUNK)    // 64
#define NSPLIT   8                  // row-splits per chunk (NSLICE removed: full row/wave)
#define AWAVES   8                  // waves per accum block
#define WSLOTS   (NSPLIT * AWAVES)  // 64 wave-slots per chunk
#define SPAN     (CHUNK / WSLOTS)   // 32 rows nominal per wave-slot
#define ATHREADS 512
#define STHREADS 1024

// ---------------------------------------------------------------------------
// Kernel 0: per-chunk counting sort of labels (labels-only). Emits class-
// sorted global row ids, class offsets, counts, and 64 per-chunk wave-slot
// class spans (slot s owns classes whose segment STARTS in [32s, 32(s+1))).
// Each class belongs to exactly one slot -> every partial written exactly once.
// ---------------------------------------------------------------------------
__global__ __launch_bounds__(STHREADS) void icv_sort_kernel(
    const int* __restrict__ labels,
    int* __restrict__ rows_g,   // [NCHUNK][CHUNK] global row ids, class-sorted
    int* __restrict__ off_g,    // [NCHUNK][NCLASS+1]
    int* __restrict__ cnt_p,    // [NCHUNK][NCLASS]
    int* __restrict__ span_g,   // [NCHUNK][WSLOTS][2]
    int* __restrict__ sync_cnt)
{
    __shared__ int s_cnt[NCLASS];
    __shared__ int s_off[NCLASS + 1];
    __shared__ int s_pos[NCLASS];
    __shared__ int s_scan[128];
    __shared__ int s_rows[CHUNK];

    const int tid   = threadIdx.x;
    const int chunk = blockIdx.x;
    const int row0  = chunk * CHUNK;

    if (tid < NCLASS) s_cnt[tid] = 0;
    if (chunk == 0 && tid == 0) *sync_cnt = 0;     // re-init every call
    __syncthreads();

    const int lab0 = labels[row0 + tid];           // coalesced, 2 rows/thread
    const int lab1 = labels[row0 + STHREADS + tid];
    atomicAdd(&s_cnt[lab0], 1);
    atomicAdd(&s_cnt[lab1], 1);
    __syncthreads();

    // exclusive prefix over 100 bins (128-wide Hillis-Steele)
    if (tid < 128) s_scan[tid] = (tid < NCLASS) ? s_cnt[tid] : 0;
    __syncthreads();
    #pragma unroll
    for (int d = 1; d < 128; d <<= 1) {
        int v = 0;
        if (tid < 128) { v = s_scan[tid]; if (tid >= d) v += s_scan[tid - d]; }
        __syncthreads();
        if (tid < 128) s_scan[tid] = v;
        __syncthreads();
    }
    if (tid < NCLASS) { const int e = s_scan[tid] - s_cnt[tid]; s_off[tid] = e; s_pos[tid] = e; }
    if (tid == NCLASS) s_off[NCLASS] = CHUNK;
    __syncthreads();

    { const int p0 = atomicAdd(&s_pos[lab0], 1); s_rows[p0] = row0 + tid; }
    { const int p1 = atomicAdd(&s_pos[lab1], 1); s_rows[p1] = row0 + STHREADS + tid; }

    // wave-slot class spans: owner(c) = min(s_off[c]/SPAN, WSLOTS-1);
    // owner is non-decreasing in c -> contiguous class ranges, full partition.
    if (tid < WSLOTS) {
        int cf = NCLASS, ce = NCLASS;
        for (int c = 0; c < NCLASS; ++c) {
            int ow = s_off[c] / SPAN; if (ow > WSLOTS - 1) ow = WSLOTS - 1;
            if (ow == tid && cf == NCLASS) cf = c;
            if (ow > tid) { ce = c; break; }
        }
        if (cf > ce) cf = ce;                      // empty slot
        span_g[(chunk * WSLOTS + tid) * 2 + 0] = cf;
        span_g[(chunk * WSLOTS + tid) * 2 + 1] = ce;
    }
    __syncthreads();

    rows_g[chunk * CHUNK + tid]            = s_rows[tid];
    rows_g[chunk * CHUNK + STHREADS + tid] = s_rows[STHREADS + tid];
    if (tid < NCLASS) {
        off_g[chunk * (NCLASS + 1) + tid] = s_off[tid];
        cnt_p[chunk * NCLASS + tid]       = s_cnt[tid];
    }
    if (tid == NCLASS) off_g[chunk * (NCLASS + 1) + NCLASS] = CHUNK;
}

// ---------------------------------------------------------------------------
// Kernel 1: pure streaming accumulation, FULL-ROW granule. Grid = 64 chunks
// x 8 splits = 512 blocks of 512 threads (2 blocks/CU). Wave-slot ws =
// split*8 + wave streams its snapped class span; each row is one contiguous
// 2 KB read (2x float4 per lane), depth-4 ring (8 KB in flight per wave),
// register accumulation, per-class flush = plain coalesced stores.
// ---------------------------------------------------------------------------
__global__ __launch_bounds__(ATHREADS, 4) void icv_accum_kernel(
    const float* __restrict__ feat,     // [NROWS][DDIM]
    const int*   __restrict__ rows_g,
    const int*   __restrict__ off_g,
    const int*   __restrict__ span_g,
    float*       __restrict__ sums_p,   // [NCHUNK][NCLASS][DDIM]
    float*       __restrict__ sq_p)     // [NCHUNK][NCLASS]
{
    __shared__ int s_rows[CHUNK];       // 8 KB
    __shared__ int s_off[NCLASS + 1];

    const int tid   = threadIdx.x;
    const int wave  = tid >> 6;
    const int lane  = tid & 63;
    const int b     = blockIdx.x;
    const int chunk = b >> 3;
    const int split = b & 7;

    #pragma unroll
    for (int k = 0; k < CHUNK / ATHREADS; ++k)
        s_rows[k * ATHREADS + tid] = rows_g[chunk * CHUNK + k * ATHREADS + tid];
    if (tid < NCLASS + 1) s_off[tid] = off_g[chunk * (NCLASS + 1) + tid];
    __syncthreads();

    const int ws = split * AWAVES + wave;
    const int cf = span_g[(chunk * WSLOTS + ws) * 2 + 0];
    const int ce = span_g[(chunk * WSLOTS + ws) * 2 + 1];
    const int i0 = s_off[cf];
    const int i1 = s_off[ce];

    const float4* f4 = (const float4*)feat;        // row stride DDIM/4 = 128

    int    c    = cf;
    int    cend = (c < ce) ? s_off[c + 1] : (CHUNK + 1);
    float4 accA = make_float4(0.f, 0.f, 0.f, 0.f);
    float4 accB = make_float4(0.f, 0.f, 0.f, 0.f);
    float  sq   = 0.f;

#define LOADA(idx) f4[(size_t)s_rows[(idx)] * (DDIM / 4) + lane]
#define LOADB(idx) f4[(size_t)s_rows[(idx)] * (DDIM / 4) + 64 + lane]

#define FLUSH() do {                                                          \
        float s_ = sq;                                                        \
        s_ += __shfl_xor(s_, 32, 64); s_ += __shfl_xor(s_, 16, 64);           \
        s_ += __shfl_xor(s_,  8, 64); s_ += __shfl_xor(s_,  4, 64);           \
        s_ += __shfl_xor(s_,  2, 64); s_ += __shfl_xor(s_,  1, 64);           \
        float4* dst_ = (float4*)(sums_p                                       \
            + ((size_t)(chunk * NCLASS + c) * DDIM));                         \
        dst_[lane]      = accA;                                               \
        dst_[64 + lane] = accB;                                               \
        if (lane == 0) sq_p[chunk * NCLASS + c] = s_;                         \
        accA = make_float4(0.f, 0.f, 0.f, 0.f);                               \
        accB = make_float4(0.f, 0.f, 0.f, 0.f);                               \
        sq = 0.f;                                                             \
        ++c;                                                                  \
        cend = (c < ce) ? s_off[c + 1] : (CHUNK + 1);                         \
    } while (0)

#define STEP(K, RA, RB) {                                                     \
        const int i_ = ib + (K);                                              \
        if (i_ < i1) {                                                        \
            while (i_ >= cend) FLUSH();                                       \
            const float4 a_ = RA;                                             \
            const float4 b_ = RB;                                             \
            const int ip_ = i_ + 4;                                           \
            if (ip_ < i1) { RA = LOADA(ip_); RB = LOADB(ip_); }               \
            accA.x += a_.x; accA.y += a_.y; accA.z += a_.z; accA.w += a_.w;   \
            accB.x += b_.x; accB.y += b_.y; accB.z += b_.z; accB.w += b_.w;   \
            sq = fmaf(a_.x, a_.x, fmaf(a_.y, a_.y,                            \
                 fmaf(a_.z, a_.z, fmaf(a_.w, a_.w, sq))));                    \
            sq = fmaf(b_.x, b_.x, fmaf(b_.y, b_.y,                            \
                 fmaf(b_.z, b_.z, fmaf(b_.w, b_.w, sq))));                    \
        }                                                                     \
    }

    float4 r0a = make_float4(0.f, 0.f, 0.f, 0.f), r0b = r0a;
    float4 r1a = r0a, r1b = r0a, r2a = r0a, r2b = r0a, r3a = r0a, r3b = r0a;
    if (i0 + 0 < i1) { r0a = LOADA(i0 + 0); r0b = LOADB(i0 + 0); }
    if (i0 + 1 < i1) { r1a = LOADA(i0 + 1); r1b = LOADB(i0 + 1); }
    if (i0 + 2 < i1) { r2a = LOADA(i0 + 2); r2b = LOADB(i0 + 2); }
    if (i0 + 3 < i1) { r3a = LOADA(i0 + 3); r3b = LOADB(i0 + 3); }

    for (int ib = i0; ib < i1; ib += 4) {
        STEP(0, r0a, r0b)
        STEP(1, r1a, r1b)
        STEP(2, r2a, r2b)
        STEP(3, r3a, r3b)
    }
    while (c < ce) FLUSH();                        // tail incl. empty classes
#undef STEP
#undef FLUSH
#undef LOADA
#undef LOADB
}

// ---------------------------------------------------------------------------
// Kernel 2: per-class reduction of partials -> trace/valid, fused with the
// final valid-mean via last-block pattern (device-scope fence + atomic).
// ---------------------------------------------------------------------------
__global__ __launch_bounds__(512) void icv_reduce_kernel(
    const float* __restrict__ sums_p,   // [NCHUNK][NCLASS][DDIM]
    const float* __restrict__ sq_p,     // [NCHUNK][NCLASS]
    const int*   __restrict__ cnt_p,    // [NCHUNK][NCLASS]
    float*       __restrict__ cls_out,  // [NCLASS][2]
    int*         __restrict__ sync_cnt,
    float*       __restrict__ out)
{
    __shared__ float red[3][8];
    __shared__ float fin[2][8];
    __shared__ int   s_last;

    const int c    = blockIdx.x;
    const int t    = threadIdx.x;
    const int wave = t >> 6;
    const int lane = t & 63;

    // thread t owns column t of class c, summed over chunks
    float s = 0.f;
    const float* p = sums_p + (size_t)c * DDIM + t;
    #pragma unroll 8
    for (int ch = 0; ch < NCHUNK; ++ch)
        s += p[(size_t)ch * (NCLASS * DDIM)];

    float v1 = s * s;                                          // -> ||sum_c||^2
    float v2 = (t < NCHUNK) ? sq_p[t * NCLASS + c] : 0.f;
    float v3 = (t < NCHUNK) ? (float)cnt_p[t * NCLASS + c] : 0.f;
    #pragma unroll
    for (int off = 32; off > 0; off >>= 1) {
        v1 += __shfl_xor(v1, off, 64);
        v2 += __shfl_xor(v2, off, 64);
        v3 += __shfl_xor(v3, off, 64);
    }
    if (lane == 0) { red[0][wave] = v1; red[1][wave] = v2; red[2][wave] = v3; }
    __syncthreads();

    if (t == 0) {
        float n2 = 0.f, sq = 0.f, n = 0.f;
        #pragma unroll
        for (int w = 0; w < 8; ++w) { n2 += red[0][w]; sq += red[1][w]; n += red[2][w]; }
        const float safe  = fmaxf(n, 1.f);
        const float ssd   = sq - n2 / safe;        // sq - n*||sums/n||^2
        const float trace = ssd / fmaxf(n - 1.f, 1.f);
        const bool  valid = (n >= 2.f);
        cls_out[c * 2 + 0] = valid ? trace : 0.f;
        cls_out[c * 2 + 1] = valid ? 1.f : 0.f;
        __threadfence();                           // release class result
        const int done = atomicAdd(sync_cnt, 1);   // device-scope
        s_last = (done == NCLASS - 1) ? 1 : 0;
    }
    __syncthreads();

    if (s_last) {                                  // uniform across block
        __threadfence();                           // acquire others' results
        float tv = 0.f, vv = 0.f;
        if (t < NCLASS) {
            const volatile float* cv = (const volatile float*)cls_out;
            tv = cv[t * 2 + 0];
            vv = cv[t * 2 + 1];
        }
        #pragma unroll
        for (int off = 32; off > 0; off >>= 1) {
            tv += __shfl_xor(tv, off, 64);
            vv += __shfl_xor(vv, off, 64);
        }
        if (lane == 0) { fin[0][wave] = tv; fin[1][wave] = vv; }
        __syncthreads();
        if (t == 0) {
            float tot = 0.f, vc = 0.f;
            #pragma unroll
            for (int w = 0; w < 8; ++w) { tot += fin[0][w]; vc += fin[1][w]; }
            out[0] = (vc > 0.f) ? (tot / fmaxf(vc, 1.f)) : 0.f;
        }
    }
}

extern "C" void kernel_launch(void* const* d_in, const int* in_sizes, int n_in,
                              void* d_out, int out_size, void* d_ws, size_t ws_size,
                              hipStream_t stream) {
    const float* feat   = (const float*)d_in[0];
    const int*   labels = (const int*)d_in[1];
    float* out = (float*)d_out;

    // Workspace (all slots written unconditionally every call -> no memset):
    float* sums_p  = (float*)d_ws;                              // 13.1 MB
    float* sq_p    = sums_p + (size_t)NCHUNK * NCLASS * DDIM;   // 26 KB
    int*   cnt_p   = (int*)(sq_p + NCHUNK * NCLASS);            // 26 KB
    int*   rows_g  = cnt_p + NCHUNK * NCLASS;                   // 524 KB
    int*   off_g   = rows_g + NCHUNK * CHUNK;                   // 26 KB
    int*   span_g  = off_g + NCHUNK * (NCLASS + 1);             // 32 KB
    float* cls_out = (float*)(span_g + NCHUNK * WSLOTS * 2);
    int*   sync_cnt= (int*)(cls_out + NCLASS * 2);

    icv_sort_kernel<<<dim3(NCHUNK), STHREADS, 0, stream>>>(
        labels, rows_g, off_g, cnt_p, span_g, sync_cnt);
    icv_accum_kernel<<<dim3(NCHUNK * NSPLIT), ATHREADS, 0, stream>>>(
        feat, rows_g, off_g, span_g, sums_p, sq_p);
    icv_reduce_kernel<<<dim3(NCLASS), 512, 0, stream>>>(
        sums_p, sq_p, cnt_p, cls_out, sync_cnt, out);
}